// Round 1
// baseline (1522.518 us; speedup 1.0000x reference)
//
#include <hip/hip_runtime.h>
#include <stdint.h>

using u8  = unsigned char;
using s8  = signed char;
using u16 = unsigned short;
using u32 = unsigned int;
using u64 = unsigned long long;

typedef int   v4i __attribute__((ext_vector_type(4)));
typedef float v4f __attribute__((ext_vector_type(4)));
typedef short v8s __attribute__((ext_vector_type(8)));

__device__ __forceinline__ u16 f2bf(float f){
  u32 u = __builtin_bit_cast(u32, f);
  u32 r = (u + 0x7FFFu + ((u >> 16) & 1u)) >> 16;
  return (u16)r;
}
__device__ __forceinline__ float bf2f(u16 b){
  u32 u = ((u32)b) << 16;
  return __builtin_bit_cast(float, u);
}

// ---------------------------------------------------------------------------
// Quantize fp32 -> 4 signed-i8 digit planes of X = rint(x*scale).
// scale is a power of 2 => x*scale is EXACT in fp32; digits reconstruct X exactly.
// plane p stored at dig + p*n.
// ---------------------------------------------------------------------------
__global__ __launch_bounds__(256) void quant_digits(
    const float* __restrict__ in, s8* __restrict__ dig, int n, float scale, float clampv)
{
  int t = blockIdx.x * 256 + threadIdx.x;
  int n8 = n >> 3;
  if (t >= n8) return;
  const float4* inv = (const float4*)in;
  float4 a = inv[2*t], b = inv[2*t+1];
  float xs[8] = {a.x,a.y,a.z,a.w,b.x,b.y,b.z,b.w};
  u64 p0=0,p1=0,p2=0,p3=0;
#pragma unroll
  for (int j=0;j<8;j++){
    float xv = fminf(fmaxf(xs[j], -clampv), clampv);
    int X = (int)rintf(xv * scale);
    int d0 = (int)(s8)(X & 255); X = (X - d0) >> 8;
    int d1 = (int)(s8)(X & 255); X = (X - d1) >> 8;
    int d2 = (int)(s8)(X & 255); X = (X - d2) >> 8;
    int d3 = X;
    p0 |= ((u64)(u8)(s8)d0) << (8*j);
    p1 |= ((u64)(u8)(s8)d1) << (8*j);
    p2 |= ((u64)(u8)(s8)d2) << (8*j);
    p3 |= ((u64)(u8)(s8)d3) << (8*j);
  }
  u64* o = (u64*)dig;
  size_t np8 = (size_t)n8;
  o[t] = p0; o[np8 + t] = p1; o[2*np8 + t] = p2; o[3*np8 + t] = p3;
}

// ---------------------------------------------------------------------------
// Precise GEMM: C[i][o] = sum_j A[i][j]*W[o][j] + bias[o]
// A digits: scale 2^27 (4 planes, M*1024 each). W digits: scale 2^32.
// 13 i8-MFMA passes (digit classes c=i+j in [2,6]); exact i32 accumulation;
// fp64 combine. Out: float2 (hi,lo) + bf16. M=4096, N=K=1024.
// ---------------------------------------------------------------------------
#define MFMA_I8(c, a, b) asm volatile("v_mfma_i32_16x16x64_i8 %0, %1, %2, %0" : "+v"(c) : "v"(a), "v"(b))

__global__ __launch_bounds__(256) void gemm_i8(
    const s8* __restrict__ Ad, const s8* __restrict__ Wd, const float* __restrict__ bias,
    float2* __restrict__ Cf2, u16* __restrict__ Cb)
{
  __shared__ alignas(16) s8 As[4][32][80];   // +16 pad: 2-way-max LDS banking
  __shared__ alignas(16) s8 Bs[4][32][80];
  const int i0 = blockIdx.x * 32, o0 = blockIdx.y * 32;
  const int t = threadIdx.x, w = t >> 6, lane = t & 63;
  const int wr = w >> 1, wc = w & 1, l15 = lane & 15, lg = lane >> 4;
  const size_t APL = 4194304, WPL = 1048576;

  v4i c0={0,0,0,0}, c1={0,0,0,0}, c2={0,0,0,0}, c3={0,0,0,0}, c4={0,0,0,0};

  for (int kt = 0; kt < 16; ++kt){
#pragma unroll
    for (int j = 0; j < 2; ++j){
      int cid = t*2 + j;
      int p = cid >> 7, rem = cid & 127;
      int row = rem >> 2, c16 = (rem & 3) << 4;
      int4 av = *(const int4*)(Ad + (size_t)p*APL + (size_t)(i0+row)*1024 + kt*64 + c16);
      *(int4*)&As[p][row][c16] = av;
      int4 bv = *(const int4*)(Wd + (size_t)p*WPL + (size_t)(o0+row)*1024 + kt*64 + c16);
      *(int4*)&Bs[p][row][c16] = bv;
    }
    __syncthreads();
    v4i a0 = *(const v4i*)&As[0][wr*16+l15][lg*16];
    v4i a1 = *(const v4i*)&As[1][wr*16+l15][lg*16];
    v4i a2 = *(const v4i*)&As[2][wr*16+l15][lg*16];
    v4i a3 = *(const v4i*)&As[3][wr*16+l15][lg*16];
    v4i b0 = *(const v4i*)&Bs[0][wc*16+l15][lg*16];
    v4i b1 = *(const v4i*)&Bs[1][wc*16+l15][lg*16];
    v4i b2 = *(const v4i*)&Bs[2][wc*16+l15][lg*16];
    v4i b3 = *(const v4i*)&Bs[3][wc*16+l15][lg*16];
    MFMA_I8(c0, a0, b2); MFMA_I8(c0, a1, b1); MFMA_I8(c0, a2, b0);
    MFMA_I8(c1, a0, b3); MFMA_I8(c1, a1, b2); MFMA_I8(c1, a2, b1); MFMA_I8(c1, a3, b0);
    MFMA_I8(c2, a1, b3); MFMA_I8(c2, a2, b2); MFMA_I8(c2, a3, b1);
    MFMA_I8(c3, a2, b3); MFMA_I8(c3, a3, b2);
    MFMA_I8(c4, a3, b3);
    __syncthreads();
  }
  const int oc = o0 + wc*16 + l15;
  const double bv = (double)bias[oc];
#pragma unroll
  for (int e = 0; e < 4; ++e){
    // product scale 2^(27+32)=2^59; class c weight 2^(8c-59): c=2..6
    double val = (double)c0[e]*0x1p-43 + (double)c1[e]*0x1p-35 + (double)c2[e]*0x1p-27
               + (double)c3[e]*0x1p-19 + (double)c4[e]*0x1p-11 + bv;
    int orow = i0 + wr*16 + lg*4 + e;
    float hi = (float)val;
    float lo = (float)(val - (double)hi);
    Cf2[(size_t)orow*1024 + oc] = make_float2(hi, lo);
    Cb[(size_t)orow*1024 + oc]  = f2bf(hi);
  }
}

// ---------------------------------------------------------------------------
// bf16 GEMM: C[i][o] = sum_j A[i][j]*W[o][j] + bias[o], fp32 out.
// ABF16: 0 = A fp32 (convert), 1 = A already bf16 (u16).
// ---------------------------------------------------------------------------
template<int ABF16>
__global__ __launch_bounds__(256) void gemm_bf16k(
    const void* __restrict__ Ap, const float* __restrict__ W, const float* __restrict__ bias,
    float* __restrict__ C)
{
  __shared__ alignas(16) u16 As[32][72];
  __shared__ alignas(16) u16 Bs[32][72];
  const int i0 = blockIdx.x * 32, o0 = blockIdx.y * 32;
  const int t = threadIdx.x, w = t >> 6, lane = t & 63;
  const int wr = w >> 1, wc = w & 1, l15 = lane & 15, lg = lane >> 4;
  const int row = t >> 3, c8 = (t & 7) * 8;
  v4f acc = {0.f,0.f,0.f,0.f};
  for (int kt = 0; kt < 16; ++kt){
    if (ABF16){
      v8s x = *(const v8s*)((const u16*)Ap + (size_t)(i0+row)*1024 + kt*64 + c8);
      *(v8s*)&As[row][c8] = x;
    } else {
      const float* A = (const float*)Ap;
      const float4 x0 = *(const float4*)(A + (size_t)(i0+row)*1024 + kt*64 + c8);
      const float4 x1 = *(const float4*)(A + (size_t)(i0+row)*1024 + kt*64 + c8 + 4);
      v8s pk;
      pk[0]=(short)f2bf(x0.x); pk[1]=(short)f2bf(x0.y); pk[2]=(short)f2bf(x0.z); pk[3]=(short)f2bf(x0.w);
      pk[4]=(short)f2bf(x1.x); pk[5]=(short)f2bf(x1.y); pk[6]=(short)f2bf(x1.z); pk[7]=(short)f2bf(x1.w);
      *(v8s*)&As[row][c8] = pk;
    }
    {
      const float4 y0 = *(const float4*)(W + (size_t)(o0+row)*1024 + kt*64 + c8);
      const float4 y1 = *(const float4*)(W + (size_t)(o0+row)*1024 + kt*64 + c8 + 4);
      v8s pk;
      pk[0]=(short)f2bf(y0.x); pk[1]=(short)f2bf(y0.y); pk[2]=(short)f2bf(y0.z); pk[3]=(short)f2bf(y0.w);
      pk[4]=(short)f2bf(y1.x); pk[5]=(short)f2bf(y1.y); pk[6]=(short)f2bf(y1.z); pk[7]=(short)f2bf(y1.w);
      *(v8s*)&Bs[row][c8] = pk;
    }
    __syncthreads();
    v8s a0 = *(const v8s*)&As[wr*16+l15][lg*8];
    v8s a1 = *(const v8s*)&As[wr*16+l15][lg*8+32];
    v8s b0 = *(const v8s*)&Bs[wc*16+l15][lg*8];
    v8s b1 = *(const v8s*)&Bs[wc*16+l15][lg*8+32];
    acc = __builtin_amdgcn_mfma_f32_16x16x32_bf16(a0, b0, acc, 0, 0, 0);
    acc = __builtin_amdgcn_mfma_f32_16x16x32_bf16(a1, b1, acc, 0, 0, 0);
    __syncthreads();
  }
  const int oc = o0 + wc*16 + l15;
  const float bvv = bias[oc];
#pragma unroll
  for (int e=0;e<4;e++){
    int orow = i0 + wr*16 + lg*4 + e;
    C[(size_t)orow*1024 + oc] = acc[e] + bvv;
  }
}

// ---------------------------------------------------------------------------
// Fused top-k attention. Per WG: one (b,h), 16 q-rows, 512 threads (8 waves).
// Phase1: approx scores (bf16 MFMA) -> LDS. Phase2: exact 64th bf16 value via
// 16-bit key binary search. Phase3: classify auto (> t+B) / band (+-B).
// Phase4: fp64 rescore of band from float2 Q,K. Phase5: exact top fill.
// Phase6: softmax(approx scores) + PV in fp32. Output bf16 in reshape layout.
// ---------------------------------------------------------------------------
__global__ __launch_bounds__(512) void attn_topk(
    const u16* __restrict__ Qb, const u16* __restrict__ Kb,
    const float2* __restrict__ Qf2, const float2* __restrict__ Kf2,
    const float* __restrict__ Vf, u16* __restrict__ Ab)
{
  __shared__ u16    S[16][2048];     // 64 KB approx scores (bf16 bits)
  __shared__ float  probs[16][64];
  __shared__ double bex[16][64];
  __shared__ u16    sel[16][64];
  __shared__ u16    bnd[16][64];
  __shared__ int    cnts[16][2];

  const int bh = blockIdx.y;
  const size_t base = (size_t)(bh >> 4) * 2097152 + (size_t)(bh & 15) * 131072;
  const u16*   Qh = Qb + base;
  const u16*   Kh = Kb + base;
  const float2* Qf = Qf2 + base;
  const float2* Kf = Kf2 + base;
  const float*  Vh = Vf + base;
  const int q0 = blockIdx.x * 16;
  const int tid = threadIdx.x, w = tid >> 6, lane = tid & 63;
  const int l15 = lane & 15, lg = lane >> 4;

  // Phase 1: approx scores; wave w covers kk in [w*256, w*256+256)
  v8s a0 = *(const v8s*)(Qh + (q0 + l15)*64 + lg*8);
  v8s a1 = *(const v8s*)(Qh + (q0 + l15)*64 + lg*8 + 32);
  for (int kt = 0; kt < 16; ++kt){
    int kk0 = w*256 + kt*16;
    v8s b0 = *(const v8s*)(Kh + (kk0 + l15)*64 + lg*8);
    v8s b1 = *(const v8s*)(Kh + (kk0 + l15)*64 + lg*8 + 32);
    v4f acc = {0.f,0.f,0.f,0.f};
    acc = __builtin_amdgcn_mfma_f32_16x16x32_bf16(a0, b0, acc, 0, 0, 0);
    acc = __builtin_amdgcn_mfma_f32_16x16x32_bf16(a1, b1, acc, 0, 0, 0);
#pragma unroll
    for (int r = 0; r < 4; ++r) S[lg*4 + r][kk0 + l15] = f2bf(acc[r] * 0.125f);
  }
  if (tid < 32) cnts[tid >> 1][tid & 1] = 0;
  __syncthreads();

  for (int rr = 0; rr < 2; ++rr){
    const int r = w*2 + rr;     // wave w owns rows 2w, 2w+1
    // Phase 2: load 32 values/lane, sortable 16-bit keys, binary search 64th
    v8s raw0 = *(const v8s*)&S[r][lane*32 + 0];
    v8s raw1 = *(const v8s*)&S[r][lane*32 + 8];
    v8s raw2 = *(const v8s*)&S[r][lane*32 + 16];
    v8s raw3 = *(const v8s*)&S[r][lane*32 + 24];
    u32 keys[32]; float vals[32];
#pragma unroll
    for (int m = 0; m < 8; ++m){
      u16 s0 = (u16)raw0[m], s1 = (u16)raw1[m], s2 = (u16)raw2[m], s3 = (u16)raw3[m];
      vals[m]      = bf2f(s0); keys[m]      = (s0 & 0x8000u) ? (u32)((~s0) & 0xFFFFu) : (u32)(s0 | 0x8000u);
      vals[8 + m]  = bf2f(s1); keys[8 + m]  = (s1 & 0x8000u) ? (u32)((~s1) & 0xFFFFu) : (u32)(s1 | 0x8000u);
      vals[16 + m] = bf2f(s2); keys[16 + m] = (s2 & 0x8000u) ? (u32)((~s2) & 0xFFFFu) : (u32)(s2 | 0x8000u);
      vals[24 + m] = bf2f(s3); keys[24 + m] = (s3 & 0x8000u) ? (u32)((~s3) & 0xFFFFu) : (u32)(s3 | 0x8000u);
    }
    u32 t64 = 0;
    for (int bit = 15; bit >= 0; --bit){
      u32 tt = t64 | (1u << bit);
      int c = 0;
#pragma unroll
      for (int m = 0; m < 32; ++m) c += (keys[m] >= tt) ? 1 : 0;
#pragma unroll
      for (int off = 32; off; off >>= 1) c += __shfl_xor(c, off);
      if (c >= 64) t64 = tt;
    }
    u16 s64b = (t64 & 0x8000u) ? (u16)(t64 ^ 0x8000u) : (u16)((~t64) & 0xFFFFu);
    float s64f = bf2f(s64b);
    float blo = s64f - 0.0625f, bhi = s64f + 0.0625f;

    // Phase 3: classify
#pragma unroll
    for (int m = 0; m < 32; ++m){
      float vv = vals[m];
      if (vv > bhi){
        int p = atomicAdd(&cnts[r][0], 1);
        if (p < 64) sel[r][p] = (u16)(lane*32 + m);
      } else if (vv >= blo){
        int p = atomicAdd(&cnts[r][1], 1);
        if (p < 64) bnd[r][p] = (u16)(lane*32 + m);
      }
    }
    __syncthreads();
    int na = cnts[r][0]; na = na > 64 ? 64 : na;
    int nb = cnts[r][1]; nb = nb > 64 ? 64 : nb;

    // Phase 4: fp64 rescore of band candidates (lane = d)
    float2 qd = Qf[(q0 + r)*64 + lane];
    double qdd = (double)qd.x + (double)qd.y;
    for (int c = 0; c < nb; ++c){
      int ki = (int)bnd[r][c];
      float2 kd = Kf[ki*64 + lane];
      double pr = qdd * ((double)kd.x + (double)kd.y);
#pragma unroll
      for (int off = 32; off; off >>= 1) pr += __shfl_xor(pr, off);
      if (lane == 0) bex[r][c] = pr;   // monotone; /8 unnecessary for ordering
    }
    __syncthreads();

    // Phase 5: pick top (64-na) of band by (exact desc, idx asc)
    int need = 64 - na; if (need > nb) need = nb;
    double myv = (lane < nb) ? bex[r][lane] : -1.0e300;
    int    myi = (lane < nb) ? (int)bnd[r][lane] : 0x7FFFFFFF;
    for (int s = 0; s < need; ++s){
      double bv = myv; int bi = myi;
#pragma unroll
      for (int off = 32; off; off >>= 1){
        double ov = __shfl_xor(bv, off); int oi = __shfl_xor(bi, off);
        if (ov > bv || (ov == bv && oi < bi)){ bv = ov; bi = oi; }
      }
      if (myi == bi){ myv = -1.0e300; myi = 0x7FFFFFFF; }
      if (lane == 0) sel[r][na + s] = (u16)bi;
    }
    __syncthreads();

    // Phase 6: softmax over the 64 selected (approx scores)
    float sc = bf2f(S[r][sel[r][lane]]);
    float mx = sc;
#pragma unroll
    for (int off = 32; off; off >>= 1) mx = fmaxf(mx, __shfl_xor(mx, off));
    float p = expf(sc - mx);
    float Z = p;
#pragma unroll
    for (int off = 32; off; off >>= 1) Z += __shfl_xor(Z, off);
    probs[r][lane] = p / Z;
    __syncthreads();

    // Phase 7: PV (lane = d), fp32
    float o0 = 0.f, o1 = 0.f, o2 = 0.f, o3 = 0.f;
#pragma unroll
    for (int i = 0; i < 64; i += 4){
      o0 += probs[r][i+0] * Vh[(int)sel[r][i+0]*64 + lane];
      o1 += probs[r][i+1] * Vh[(int)sel[r][i+1]*64 + lane];
      o2 += probs[r][i+2] * Vh[(int)sel[r][i+2]*64 + lane];
      o3 += probs[r][i+3] * Vh[(int)sel[r][i+3]*64 + lane];
    }
    Ab[base + (size_t)(q0 + r)*64 + lane] = f2bf((o0 + o1) + (o2 + o3));
    __syncthreads();
  }
}

// ---------------------------------------------------------------------------
extern "C" void kernel_launch(void* const* d_in, const int* in_sizes, int n_in,
                              void* d_out, int out_size, void* d_ws, size_t ws_size,
                              hipStream_t stream)
{
  (void)in_sizes; (void)n_in; (void)out_size; (void)ws_size;
  const float* q  = (const float*)d_in[0];
  const float* k  = (const float*)d_in[1];
  const float* v  = (const float*)d_in[2];
  const float* Wq = (const float*)d_in[3];
  const float* bq = (const float*)d_in[4];
  const float* Wk = (const float*)d_in[5];
  const float* bk = (const float*)d_in[6];
  const float* Wv = (const float*)d_in[7];
  const float* bv = (const float*)d_in[8];
  const float* Wo = (const float*)d_in[9];
  const float* bo = (const float*)d_in[10];

  char* ws = (char*)d_ws;
  const size_t MB = 1048576;
  float2* Qf2 = (float2*)(ws);              // 32 MB
  float2* Kf2 = (float2*)(ws + 32*MB);      // 32 MB
  u16*    Qb  = (u16*)  (ws + 64*MB);       // 8 MB
  u16*    Kb  = (u16*)  (ws + 72*MB);       // 8 MB
  float*  Vf  = (float*)(ws + 80*MB);       // 16 MB
  u16*    Abf = (u16*)  (ws + 96*MB);       // 8 MB
  s8*     dact= (s8*)   (ws + 104*MB);      // 16 MB (4 planes)
  s8*     dw  = (s8*)   (ws + 120*MB);      // 4 MB  (4 planes)  -> total 124 MB

  // Q = q @ Wq^T + bq  (exact fixed-point path)
  quant_digits<<<2048, 256, 0, stream>>>(q,  dact, 4194304, 134217728.0f, 7.75f);    // 2^27
  quant_digits<<<512,  256, 0, stream>>>(Wq, dw,   1048576, 4294967296.0f, 0.2495f); // 2^32
  gemm_i8<<<dim3(128, 32), 256, 0, stream>>>(dact, dw, bq, Qf2, Qb);
  // K
  quant_digits<<<2048, 256, 0, stream>>>(k,  dact, 4194304, 134217728.0f, 7.75f);
  quant_digits<<<512,  256, 0, stream>>>(Wk, dw,   1048576, 4294967296.0f, 0.2495f);
  gemm_i8<<<dim3(128, 32), 256, 0, stream>>>(dact, dw, bk, Kf2, Kb);
  // V (bf16-grade is fine)
  gemm_bf16k<0><<<dim3(128, 32), 256, 0, stream>>>(v, Wv, bv, Vf);
  // fused top-k attention
  attn_topk<<<dim3(128, 32), 512, 0, stream>>>(Qb, Kb, Qf2, Kf2, Vf, Abf);
  // out = attn @ Wo^T + bo
  gemm_bf16k<1><<<dim3(128, 32), 256, 0, stream>>>(Abf, Wo, bo, (float*)d_out);
}

// Round 2
// 826.988 us; speedup vs baseline: 1.8410x; 1.8410x over previous
//
#include <hip/hip_runtime.h>
#include <stdint.h>

using u8  = unsigned char;
using s8  = signed char;
using u16 = unsigned short;
using u32 = unsigned int;
using u64 = unsigned long long;

typedef int   v4i __attribute__((ext_vector_type(4)));
typedef float v4f __attribute__((ext_vector_type(4)));
typedef short v8s __attribute__((ext_vector_type(8)));

__device__ __forceinline__ u16 f2bf(float f){
  u32 u = __builtin_bit_cast(u32, f);
  u32 r = (u + 0x7FFFu + ((u >> 16) & 1u)) >> 16;
  return (u16)r;
}
__device__ __forceinline__ float bf2f(u16 b){
  u32 u = ((u32)b) << 16;
  return __builtin_bit_cast(float, u);
}

// ---------------------------------------------------------------------------
// Quantize fp32 -> 4 signed-i8 digit planes of X = rint(x*scale).
// scale is a power of 2 => x*scale is EXACT in fp32; digits reconstruct X exactly.
// ---------------------------------------------------------------------------
__global__ __launch_bounds__(256) void quant_digits(
    const float* __restrict__ in, s8* __restrict__ dig, int n, float scale, float clampv)
{
  int t = blockIdx.x * 256 + threadIdx.x;
  int n8 = n >> 3;
  if (t >= n8) return;
  const float4* inv = (const float4*)in;
  float4 a = inv[2*t], b = inv[2*t+1];
  float xs[8] = {a.x,a.y,a.z,a.w,b.x,b.y,b.z,b.w};
  u64 p0=0,p1=0,p2=0,p3=0;
#pragma unroll
  for (int j=0;j<8;j++){
    float xv = fminf(fmaxf(xs[j], -clampv), clampv);
    int X = (int)rintf(xv * scale);
    int d0 = (int)(s8)(X & 255); X = (X - d0) >> 8;
    int d1 = (int)(s8)(X & 255); X = (X - d1) >> 8;
    int d2 = (int)(s8)(X & 255); X = (X - d2) >> 8;
    int d3 = X;
    p0 |= ((u64)(u8)(s8)d0) << (8*j);
    p1 |= ((u64)(u8)(s8)d1) << (8*j);
    p2 |= ((u64)(u8)(s8)d2) << (8*j);
    p3 |= ((u64)(u8)(s8)d3) << (8*j);
  }
  u64* o = (u64*)dig;
  size_t np8 = (size_t)n8;
  o[t] = p0; o[np8 + t] = p1; o[2*np8 + t] = p2; o[3*np8 + t] = p3;
}

// ---------------------------------------------------------------------------
// Precise GEMM via exact fixed-point i8 MFMA (13 digit-class passes), fp64
// combine. Out: float2 (hi,lo) + bf16.
// ---------------------------------------------------------------------------
#define MFMA_I8(c, a, b) asm volatile("v_mfma_i32_16x16x64_i8 %0, %1, %2, %0" : "+v"(c) : "v"(a), "v"(b))

__global__ __launch_bounds__(256) void gemm_i8(
    const s8* __restrict__ Ad, const s8* __restrict__ Wd, const float* __restrict__ bias,
    float2* __restrict__ Cf2, u16* __restrict__ Cb)
{
  __shared__ alignas(16) s8 As[4][32][80];
  __shared__ alignas(16) s8 Bs[4][32][80];
  const int i0 = blockIdx.x * 32, o0 = blockIdx.y * 32;
  const int t = threadIdx.x, w = t >> 6, lane = t & 63;
  const int wr = w >> 1, wc = w & 1, l15 = lane & 15, lg = lane >> 4;
  const size_t APL = 4194304, WPL = 1048576;

  v4i c0={0,0,0,0}, c1={0,0,0,0}, c2={0,0,0,0}, c3={0,0,0,0}, c4={0,0,0,0};

  for (int kt = 0; kt < 16; ++kt){
#pragma unroll
    for (int j = 0; j < 2; ++j){
      int cid = t*2 + j;
      int p = cid >> 7, rem = cid & 127;
      int row = rem >> 2, c16 = (rem & 3) << 4;
      int4 av = *(const int4*)(Ad + (size_t)p*APL + (size_t)(i0+row)*1024 + kt*64 + c16);
      *(int4*)&As[p][row][c16] = av;
      int4 bv = *(const int4*)(Wd + (size_t)p*WPL + (size_t)(o0+row)*1024 + kt*64 + c16);
      *(int4*)&Bs[p][row][c16] = bv;
    }
    __syncthreads();
    v4i a0 = *(const v4i*)&As[0][wr*16+l15][lg*16];
    v4i a1 = *(const v4i*)&As[1][wr*16+l15][lg*16];
    v4i a2 = *(const v4i*)&As[2][wr*16+l15][lg*16];
    v4i a3 = *(const v4i*)&As[3][wr*16+l15][lg*16];
    v4i b0 = *(const v4i*)&Bs[0][wc*16+l15][lg*16];
    v4i b1 = *(const v4i*)&Bs[1][wc*16+l15][lg*16];
    v4i b2 = *(const v4i*)&Bs[2][wc*16+l15][lg*16];
    v4i b3 = *(const v4i*)&Bs[3][wc*16+l15][lg*16];
    MFMA_I8(c0, a0, b2); MFMA_I8(c0, a1, b1); MFMA_I8(c0, a2, b0);
    MFMA_I8(c1, a0, b3); MFMA_I8(c1, a1, b2); MFMA_I8(c1, a2, b1); MFMA_I8(c1, a3, b0);
    MFMA_I8(c2, a1, b3); MFMA_I8(c2, a2, b2); MFMA_I8(c2, a3, b1);
    MFMA_I8(c3, a2, b3); MFMA_I8(c3, a3, b2);
    MFMA_I8(c4, a3, b3);
    __syncthreads();
  }
  const int oc = o0 + wc*16 + l15;
  const double bv = (double)bias[oc];
#pragma unroll
  for (int e = 0; e < 4; ++e){
    double val = (double)c0[e]*0x1p-43 + (double)c1[e]*0x1p-35 + (double)c2[e]*0x1p-27
               + (double)c3[e]*0x1p-19 + (double)c4[e]*0x1p-11 + bv;
    int orow = i0 + wr*16 + lg*4 + e;
    float hi = (float)val;
    float lo = (float)(val - (double)hi);
    Cf2[(size_t)orow*1024 + oc] = make_float2(hi, lo);
    Cb[(size_t)orow*1024 + oc]  = f2bf(hi);
  }
}

// ---------------------------------------------------------------------------
// bf16 GEMM (A fp32->bf16 or A bf16), fp32 out.
// ---------------------------------------------------------------------------
template<int ABF16>
__global__ __launch_bounds__(256) void gemm_bf16k(
    const void* __restrict__ Ap, const float* __restrict__ W, const float* __restrict__ bias,
    float* __restrict__ C)
{
  __shared__ alignas(16) u16 As[32][72];
  __shared__ alignas(16) u16 Bs[32][72];
  const int i0 = blockIdx.x * 32, o0 = blockIdx.y * 32;
  const int t = threadIdx.x, w = t >> 6, lane = t & 63;
  const int wr = w >> 1, wc = w & 1, l15 = lane & 15, lg = lane >> 4;
  const int row = t >> 3, c8 = (t & 7) * 8;
  v4f acc = {0.f,0.f,0.f,0.f};
  for (int kt = 0; kt < 16; ++kt){
    if (ABF16){
      v8s x = *(const v8s*)((const u16*)Ap + (size_t)(i0+row)*1024 + kt*64 + c8);
      *(v8s*)&As[row][c8] = x;
    } else {
      const float* A = (const float*)Ap;
      const float4 x0 = *(const float4*)(A + (size_t)(i0+row)*1024 + kt*64 + c8);
      const float4 x1 = *(const float4*)(A + (size_t)(i0+row)*1024 + kt*64 + c8 + 4);
      v8s pk;
      pk[0]=(short)f2bf(x0.x); pk[1]=(short)f2bf(x0.y); pk[2]=(short)f2bf(x0.z); pk[3]=(short)f2bf(x0.w);
      pk[4]=(short)f2bf(x1.x); pk[5]=(short)f2bf(x1.y); pk[6]=(short)f2bf(x1.z); pk[7]=(short)f2bf(x1.w);
      *(v8s*)&As[row][c8] = pk;
    }
    {
      const float4 y0 = *(const float4*)(W + (size_t)(o0+row)*1024 + kt*64 + c8);
      const float4 y1 = *(const float4*)(W + (size_t)(o0+row)*1024 + kt*64 + c8 + 4);
      v8s pk;
      pk[0]=(short)f2bf(y0.x); pk[1]=(short)f2bf(y0.y); pk[2]=(short)f2bf(y0.z); pk[3]=(short)f2bf(y0.w);
      pk[4]=(short)f2bf(y1.x); pk[5]=(short)f2bf(y1.y); pk[6]=(short)f2bf(y1.z); pk[7]=(short)f2bf(y1.w);
      *(v8s*)&Bs[row][c8] = pk;
    }
    __syncthreads();
    v8s a0 = *(const v8s*)&As[wr*16+l15][lg*8];
    v8s a1 = *(const v8s*)&As[wr*16+l15][lg*8+32];
    v8s b0 = *(const v8s*)&Bs[wc*16+l15][lg*8];
    v8s b1 = *(const v8s*)&Bs[wc*16+l15][lg*8+32];
    acc = __builtin_amdgcn_mfma_f32_16x16x32_bf16(a0, b0, acc, 0, 0, 0);
    acc = __builtin_amdgcn_mfma_f32_16x16x32_bf16(a1, b1, acc, 0, 0, 0);
    __syncthreads();
  }
  const int oc = o0 + wc*16 + l15;
  const float bvv = bias[oc];
#pragma unroll
  for (int e=0;e<4;e++){
    int orow = i0 + wr*16 + lg*4 + e;
    C[(size_t)orow*1024 + oc] = acc[e] + bvv;
  }
}

// ---------------------------------------------------------------------------
// Fused top-k attention, round 2:
//  - single __syncthreads (after phase 1); all row scratch is wave-private
//  - bex removed from LDS (candidate-per-lane fp64 rescore, no shfl chains)
//  - LDS 72.2KB -> 2 WG/CU
//  - XCD swizzle: each XCD runs 4 heads sequentially (K/V/Kf2 ~1.8MB in L2)
// ---------------------------------------------------------------------------
__global__ __launch_bounds__(512, 4) void attn_topk(
    const u16* __restrict__ Qb, const u16* __restrict__ Kb,
    const float2* __restrict__ Qf2, const float2* __restrict__ Kf2,
    const float* __restrict__ Vf, u16* __restrict__ Ab)
{
  __shared__ u16    S[16][2048];     // 64 KB approx scores (bf16 bits)
  __shared__ float  probsS[16][64];
  __shared__ u16    selS[16][64];
  __shared__ u16    bndS[16][64];
  __shared__ int    cnts[16][2];

  // XCD-aware swizzle: linear id -> (bh, qb) with bh grouped per XCD
  const int lid = blockIdx.y * 128 + blockIdx.x;
  const int bh  = (lid & 7) * 4 + (lid >> 10);
  const int qb  = (lid >> 3) & 127;

  const size_t base = (size_t)(bh >> 4) * 2097152 + (size_t)(bh & 15) * 131072;
  const u16*   Qh = Qb + base;
  const u16*   Kh = Kb + base;
  const float2* Qf = Qf2 + base;
  const float2* Kf = Kf2 + base;
  const float*  Vh = Vf + base;
  const int q0 = qb * 16;
  const int tid = threadIdx.x, w = tid >> 6, lane = tid & 63;
  const int l15 = lane & 15, lg = lane >> 4;

  // Phase 1: approx scores; wave w covers kk in [w*256, w*256+256)
  v8s a0 = *(const v8s*)(Qh + (q0 + l15)*64 + lg*8);
  v8s a1 = *(const v8s*)(Qh + (q0 + l15)*64 + lg*8 + 32);
  for (int kt = 0; kt < 16; ++kt){
    int kk0 = w*256 + kt*16;
    v8s b0 = *(const v8s*)(Kh + (kk0 + l15)*64 + lg*8);
    v8s b1 = *(const v8s*)(Kh + (kk0 + l15)*64 + lg*8 + 32);
    v4f acc = {0.f,0.f,0.f,0.f};
    acc = __builtin_amdgcn_mfma_f32_16x16x32_bf16(a0, b0, acc, 0, 0, 0);
    acc = __builtin_amdgcn_mfma_f32_16x16x32_bf16(a1, b1, acc, 0, 0, 0);
#pragma unroll
    for (int e = 0; e < 4; ++e) S[lg*4 + e][kk0 + l15] = f2bf(acc[e] * 0.125f);
  }
  if (tid < 32) cnts[tid >> 1][tid & 1] = 0;
  __syncthreads();   // the ONLY block-wide barrier

  for (int rr = 0; rr < 2; ++rr){
    const int r = w*2 + rr;     // wave w owns rows 2w, 2w+1 exclusively
    // Phase 2: 32 values/lane -> sortable 16-bit keys, binary search 64th
    v8s raw0 = *(const v8s*)&S[r][lane*32 + 0];
    v8s raw1 = *(const v8s*)&S[r][lane*32 + 8];
    v8s raw2 = *(const v8s*)&S[r][lane*32 + 16];
    v8s raw3 = *(const v8s*)&S[r][lane*32 + 24];
    u32 keys[32]; float vals[32];
#pragma unroll
    for (int m = 0; m < 8; ++m){
      u16 s0 = (u16)raw0[m], s1 = (u16)raw1[m], s2 = (u16)raw2[m], s3 = (u16)raw3[m];
      vals[m]      = bf2f(s0); keys[m]      = (s0 & 0x8000u) ? (u32)((~s0) & 0xFFFFu) : (u32)(s0 | 0x8000u);
      vals[8 + m]  = bf2f(s1); keys[8 + m]  = (s1 & 0x8000u) ? (u32)((~s1) & 0xFFFFu) : (u32)(s1 | 0x8000u);
      vals[16 + m] = bf2f(s2); keys[16 + m] = (s2 & 0x8000u) ? (u32)((~s2) & 0xFFFFu) : (u32)(s2 | 0x8000u);
      vals[24 + m] = bf2f(s3); keys[24 + m] = (s3 & 0x8000u) ? (u32)((~s3) & 0xFFFFu) : (u32)(s3 | 0x8000u);
    }
    u32 t64 = 0;
    for (int bit = 15; bit >= 0; --bit){
      u32 tt = t64 | (1u << bit);
      int c = 0;
#pragma unroll
      for (int m = 0; m < 32; ++m) c += (keys[m] >= tt) ? 1 : 0;
#pragma unroll
      for (int off = 32; off; off >>= 1) c += __shfl_xor(c, off);
      if (c >= 64) t64 = tt;
    }
    u16 s64b = (t64 & 0x8000u) ? (u16)(t64 ^ 0x8000u) : (u16)((~t64) & 0xFFFFu);
    float s64f = bf2f(s64b);
    float blo = s64f - 0.0625f, bhi = s64f + 0.0625f;

    // Phase 3: classify auto (> bhi) / band ([blo,bhi])
#pragma unroll
    for (int m = 0; m < 32; ++m){
      float vv = vals[m];
      if (vv > bhi){
        int p = atomicAdd(&cnts[r][0], 1);
        if (p < 64) selS[r][p] = (u16)(lane*32 + m);
      } else if (vv >= blo){
        int p = atomicAdd(&cnts[r][1], 1);
        if (p < 64) bndS[r][p] = (u16)(lane*32 + m);
      }
    }
    asm volatile("s_waitcnt lgkmcnt(0)" ::: "memory");
    __builtin_amdgcn_sched_barrier(0);
    int na = cnts[r][0]; na = na > 64 ? 64 : na;
    int nb = cnts[r][1]; nb = nb > 64 ? 64 : nb;

    // Phase 4: fp64 rescore, candidate-per-lane (no reduction chains)
    float2 qd2 = Qf[(q0 + r)*64 + lane];
    double qAll = (double)qd2.x + (double)qd2.y;   // lane holds Q[q][lane]
    int ki = (lane < nb) ? (int)bndS[r][lane] : 0;
    const float4* Kr4 = (const float4*)(Kf + (size_t)ki*64);
    double acc0 = 0.0, acc1 = 0.0;
#pragma unroll 8
    for (int d2 = 0; d2 < 32; ++d2){
      float4 kv = Kr4[d2];
      double qv0 = __shfl(qAll, 2*d2);
      double qv1 = __shfl(qAll, 2*d2 + 1);
      acc0 += qv0 * ((double)kv.x + (double)kv.y);
      acc1 += qv1 * ((double)kv.z + (double)kv.w);
    }
    double myv = (lane < nb) ? (acc0 + acc1) : -1.0e300;
    int    myi = (lane < nb) ? ki : 0x7FFFFFFF;

    // Phase 5: pick top (64-na) of band by (exact desc, idx asc)
    int need = 64 - na; if (need > nb) need = nb;
    for (int s = 0; s < need; ++s){
      double bv = myv; int bi = myi;
#pragma unroll
      for (int off = 32; off; off >>= 1){
        double ov = __shfl_xor(bv, off); int oi = __shfl_xor(bi, off);
        if (ov > bv || (ov == bv && oi < bi)){ bv = ov; bi = oi; }
      }
      if (myi == bi){ myv = -1.0e300; myi = 0x7FFFFFFF; }
      if (lane == 0) selS[r][na + s] = (u16)bi;
    }
    asm volatile("s_waitcnt lgkmcnt(0)" ::: "memory");
    __builtin_amdgcn_sched_barrier(0);

    // Phase 6: softmax over the 64 selected (approx scores)
    float sc = bf2f(S[r][selS[r][lane]]);
    float mx = sc;
#pragma unroll
    for (int off = 32; off; off >>= 1) mx = fmaxf(mx, __shfl_xor(mx, off));
    float p = expf(sc - mx);
    float Z = p;
#pragma unroll
    for (int off = 32; off; off >>= 1) Z += __shfl_xor(Z, off);
    probsS[r][lane] = p / Z;
    asm volatile("s_waitcnt lgkmcnt(0)" ::: "memory");
    __builtin_amdgcn_sched_barrier(0);

    // Phase 7: PV (lane = d), fp32
    float o0 = 0.f, o1 = 0.f, o2 = 0.f, o3 = 0.f;
#pragma unroll
    for (int i = 0; i < 64; i += 4){
      o0 += probsS[r][i+0] * Vh[(int)selS[r][i+0]*64 + lane];
      o1 += probsS[r][i+1] * Vh[(int)selS[r][i+1]*64 + lane];
      o2 += probsS[r][i+2] * Vh[(int)selS[r][i+2]*64 + lane];
      o3 += probsS[r][i+3] * Vh[(int)selS[r][i+3]*64 + lane];
    }
    Ab[base + (size_t)(q0 + r)*64 + lane] = f2bf((o0 + o1) + (o2 + o3));
  }
}

// ---------------------------------------------------------------------------
extern "C" void kernel_launch(void* const* d_in, const int* in_sizes, int n_in,
                              void* d_out, int out_size, void* d_ws, size_t ws_size,
                              hipStream_t stream)
{
  (void)in_sizes; (void)n_in; (void)out_size; (void)ws_size;
  const float* q  = (const float*)d_in[0];
  const float* k  = (const float*)d_in[1];
  const float* v  = (const float*)d_in[2];
  const float* Wq = (const float*)d_in[3];
  const float* bq = (const float*)d_in[4];
  const float* Wk = (const float*)d_in[5];
  const float* bk = (const float*)d_in[6];
  const float* Wv = (const float*)d_in[7];
  const float* bv = (const float*)d_in[8];
  const float* Wo = (const float*)d_in[9];
  const float* bo = (const float*)d_in[10];

  char* ws = (char*)d_ws;
  const size_t MB = 1048576;
  float2* Qf2 = (float2*)(ws);              // 32 MB
  float2* Kf2 = (float2*)(ws + 32*MB);      // 32 MB
  u16*    Qb  = (u16*)  (ws + 64*MB);       // 8 MB
  u16*    Kb  = (u16*)  (ws + 72*MB);       // 8 MB
  float*  Vf  = (float*)(ws + 80*MB);       // 16 MB
  u16*    Abf = (u16*)  (ws + 96*MB);       // 8 MB
  s8*     dact= (s8*)   (ws + 104*MB);      // 16 MB (4 planes)
  s8*     dw  = (s8*)   (ws + 120*MB);      // 4 MB  (4 planes)

  quant_digits<<<2048, 256, 0, stream>>>(q,  dact, 4194304, 134217728.0f, 7.75f);    // 2^27
  quant_digits<<<512,  256, 0, stream>>>(Wq, dw,   1048576, 4294967296.0f, 0.2495f); // 2^32
  gemm_i8<<<dim3(128, 32), 256, 0, stream>>>(dact, dw, bq, Qf2, Qb);
  quant_digits<<<2048, 256, 0, stream>>>(k,  dact, 4194304, 134217728.0f, 7.75f);
  quant_digits<<<512,  256, 0, stream>>>(Wk, dw,   1048576, 4294967296.0f, 0.2495f);
  gemm_i8<<<dim3(128, 32), 256, 0, stream>>>(dact, dw, bk, Kf2, Kb);
  gemm_bf16k<0><<<dim3(128, 32), 256, 0, stream>>>(v, Wv, bv, Vf);
  attn_topk<<<dim3(128, 32), 512, 0, stream>>>(Qb, Kb, Qf2, Kf2, Vf, Abf);
  gemm_bf16k<1><<<dim3(128, 32), 256, 0, stream>>>(Abf, Wo, bo, (float*)d_out);
}

// Round 3
// 808.370 us; speedup vs baseline: 1.8834x; 1.0230x over previous
//
#include <hip/hip_runtime.h>
#include <stdint.h>

using u8  = unsigned char;
using s8  = signed char;
using u16 = unsigned short;
using u32 = unsigned int;
using u64 = unsigned long long;

typedef int   v4i __attribute__((ext_vector_type(4)));
typedef float v4f __attribute__((ext_vector_type(4)));
typedef short v8s __attribute__((ext_vector_type(8)));

__device__ __forceinline__ u16 f2bf(float f){
  u32 u = __builtin_bit_cast(u32, f);
  u32 r = (u + 0x7FFFu + ((u >> 16) & 1u)) >> 16;
  return (u16)r;
}
__device__ __forceinline__ float bf2f(u16 b){
  u32 u = ((u32)b) << 16;
  return __builtin_bit_cast(float, u);
}

// ---------------------------------------------------------------------------
// Quantize fp32 -> 4 signed-i8 digit planes of X = rint(x*scale). Exact.
// ---------------------------------------------------------------------------
__global__ __launch_bounds__(256) void quant_digits(
    const float* __restrict__ in, s8* __restrict__ dig, int n, float scale, float clampv)
{
  int t = blockIdx.x * 256 + threadIdx.x;
  int n8 = n >> 3;
  if (t >= n8) return;
  const float4* inv = (const float4*)in;
  float4 a = inv[2*t], b = inv[2*t+1];
  float xs[8] = {a.x,a.y,a.z,a.w,b.x,b.y,b.z,b.w};
  u64 p0=0,p1=0,p2=0,p3=0;
#pragma unroll
  for (int j=0;j<8;j++){
    float xv = fminf(fmaxf(xs[j], -clampv), clampv);
    int X = (int)rintf(xv * scale);
    int d0 = (int)(s8)(X & 255); X = (X - d0) >> 8;
    int d1 = (int)(s8)(X & 255); X = (X - d1) >> 8;
    int d2 = (int)(s8)(X & 255); X = (X - d2) >> 8;
    int d3 = X;
    p0 |= ((u64)(u8)(s8)d0) << (8*j);
    p1 |= ((u64)(u8)(s8)d1) << (8*j);
    p2 |= ((u64)(u8)(s8)d2) << (8*j);
    p3 |= ((u64)(u8)(s8)d3) << (8*j);
  }
  u64* o = (u64*)dig;
  size_t np8 = (size_t)n8;
  o[t] = p0; o[np8 + t] = p1; o[2*np8 + t] = p2; o[3*np8 + t] = p3;
}

// ---------------------------------------------------------------------------
// Precise GEMM via exact fixed-point i8 MFMA. Epilogue writes:
//   Cd  : exact double value
//   Cb  : bf16 hi
//   Cl  : bf16 lo (residual) -> enables 3-pass bf16 MFMA approx (err ~3e-4)
// ---------------------------------------------------------------------------
#define MFMA_I8(c, a, b) asm volatile("v_mfma_i32_16x16x64_i8 %0, %1, %2, %0" : "+v"(c) : "v"(a), "v"(b))

__global__ __launch_bounds__(256) void gemm_i8(
    const s8* __restrict__ Ad, const s8* __restrict__ Wd, const float* __restrict__ bias,
    double* __restrict__ Cd, u16* __restrict__ Cb, u16* __restrict__ Cl)
{
  __shared__ alignas(16) s8 As[4][32][80];
  __shared__ alignas(16) s8 Bs[4][32][80];
  const int i0 = blockIdx.x * 32, o0 = blockIdx.y * 32;
  const int t = threadIdx.x, w = t >> 6, lane = t & 63;
  const int wr = w >> 1, wc = w & 1, l15 = lane & 15, lg = lane >> 4;
  const size_t APL = 4194304, WPL = 1048576;

  v4i c0={0,0,0,0}, c1={0,0,0,0}, c2={0,0,0,0}, c3={0,0,0,0}, c4={0,0,0,0};

  for (int kt = 0; kt < 16; ++kt){
#pragma unroll
    for (int j = 0; j < 2; ++j){
      int cid = t*2 + j;
      int p = cid >> 7, rem = cid & 127;
      int row = rem >> 2, c16 = (rem & 3) << 4;
      int4 av = *(const int4*)(Ad + (size_t)p*APL + (size_t)(i0+row)*1024 + kt*64 + c16);
      *(int4*)&As[p][row][c16] = av;
      int4 bv = *(const int4*)(Wd + (size_t)p*WPL + (size_t)(o0+row)*1024 + kt*64 + c16);
      *(int4*)&Bs[p][row][c16] = bv;
    }
    __syncthreads();
    v4i a0 = *(const v4i*)&As[0][wr*16+l15][lg*16];
    v4i a1 = *(const v4i*)&As[1][wr*16+l15][lg*16];
    v4i a2 = *(const v4i*)&As[2][wr*16+l15][lg*16];
    v4i a3 = *(const v4i*)&As[3][wr*16+l15][lg*16];
    v4i b0 = *(const v4i*)&Bs[0][wc*16+l15][lg*16];
    v4i b1 = *(const v4i*)&Bs[1][wc*16+l15][lg*16];
    v4i b2 = *(const v4i*)&Bs[2][wc*16+l15][lg*16];
    v4i b3 = *(const v4i*)&Bs[3][wc*16+l15][lg*16];
    MFMA_I8(c0, a0, b2); MFMA_I8(c0, a1, b1); MFMA_I8(c0, a2, b0);
    MFMA_I8(c1, a0, b3); MFMA_I8(c1, a1, b2); MFMA_I8(c1, a2, b1); MFMA_I8(c1, a3, b0);
    MFMA_I8(c2, a1, b3); MFMA_I8(c2, a2, b2); MFMA_I8(c2, a3, b1);
    MFMA_I8(c3, a2, b3); MFMA_I8(c3, a3, b2);
    MFMA_I8(c4, a3, b3);
    __syncthreads();
  }
  const int oc = o0 + wc*16 + l15;
  const double bv = (double)bias[oc];
#pragma unroll
  for (int e = 0; e < 4; ++e){
    double val = (double)c0[e]*0x1p-43 + (double)c1[e]*0x1p-35 + (double)c2[e]*0x1p-27
               + (double)c3[e]*0x1p-19 + (double)c4[e]*0x1p-11 + bv;
    int orow = i0 + wr*16 + lg*4 + e;
    size_t idx = (size_t)orow*1024 + oc;
    Cd[idx] = val;
    float hi = (float)val;
    u16 hb = f2bf(hi);
    float lof = (float)(val - (double)bf2f(hb));
    Cb[idx] = hb;
    Cl[idx] = f2bf(lof);
  }
}

// ---------------------------------------------------------------------------
// bf16 GEMM (A fp32->bf16 or A bf16), out fp32 or bf16.
// ---------------------------------------------------------------------------
template<int ABF16, int OUTBF>
__global__ __launch_bounds__(256) void gemm_bf16k(
    const void* __restrict__ Ap, const float* __restrict__ W, const float* __restrict__ bias,
    void* __restrict__ C)
{
  __shared__ alignas(16) u16 As[32][72];
  __shared__ alignas(16) u16 Bs[32][72];
  const int i0 = blockIdx.x * 32, o0 = blockIdx.y * 32;
  const int t = threadIdx.x, w = t >> 6, lane = t & 63;
  const int wr = w >> 1, wc = w & 1, l15 = lane & 15, lg = lane >> 4;
  const int row = t >> 3, c8 = (t & 7) * 8;
  v4f acc = {0.f,0.f,0.f,0.f};
  for (int kt = 0; kt < 16; ++kt){
    if (ABF16){
      v8s x = *(const v8s*)((const u16*)Ap + (size_t)(i0+row)*1024 + kt*64 + c8);
      *(v8s*)&As[row][c8] = x;
    } else {
      const float* A = (const float*)Ap;
      const float4 x0 = *(const float4*)(A + (size_t)(i0+row)*1024 + kt*64 + c8);
      const float4 x1 = *(const float4*)(A + (size_t)(i0+row)*1024 + kt*64 + c8 + 4);
      v8s pk;
      pk[0]=(short)f2bf(x0.x); pk[1]=(short)f2bf(x0.y); pk[2]=(short)f2bf(x0.z); pk[3]=(short)f2bf(x0.w);
      pk[4]=(short)f2bf(x1.x); pk[5]=(short)f2bf(x1.y); pk[6]=(short)f2bf(x1.z); pk[7]=(short)f2bf(x1.w);
      *(v8s*)&As[row][c8] = pk;
    }
    {
      const float4 y0 = *(const float4*)(W + (size_t)(o0+row)*1024 + kt*64 + c8);
      const float4 y1 = *(const float4*)(W + (size_t)(o0+row)*1024 + kt*64 + c8 + 4);
      v8s pk;
      pk[0]=(short)f2bf(y0.x); pk[1]=(short)f2bf(y0.y); pk[2]=(short)f2bf(y0.z); pk[3]=(short)f2bf(y0.w);
      pk[4]=(short)f2bf(y1.x); pk[5]=(short)f2bf(y1.y); pk[6]=(short)f2bf(y1.z); pk[7]=(short)f2bf(y1.w);
      *(v8s*)&Bs[row][c8] = pk;
    }
    __syncthreads();
    v8s a0 = *(const v8s*)&As[wr*16+l15][lg*8];
    v8s a1 = *(const v8s*)&As[wr*16+l15][lg*8+32];
    v8s b0 = *(const v8s*)&Bs[wc*16+l15][lg*8];
    v8s b1 = *(const v8s*)&Bs[wc*16+l15][lg*8+32];
    acc = __builtin_amdgcn_mfma_f32_16x16x32_bf16(a0, b0, acc, 0, 0, 0);
    acc = __builtin_amdgcn_mfma_f32_16x16x32_bf16(a1, b1, acc, 0, 0, 0);
    __syncthreads();
  }
  const int oc = o0 + wc*16 + l15;
  const float bvv = bias[oc];
#pragma unroll
  for (int e=0;e<4;e++){
    int orow = i0 + wr*16 + lg*4 + e;
    size_t idx = (size_t)orow*1024 + oc;
    if (OUTBF) ((u16*)C)[idx] = f2bf(acc[e] + bvv);
    else       ((float*)C)[idx] = acc[e] + bvv;
  }
}

// ---------------------------------------------------------------------------
// Fused top-k attention, round 3:
//  - 3-pass bf16 MFMA scores (hi*hi + hi*lo + lo*hi): approx err ~3e-4
//  - ballot histogram (16 buckets, [1.5,2.4375)) replaces serial binary search
//  - provable auto/band sets with delta=0.006; rare fallback = old binsearch
//  - fp64 rescore from precomputed double Q/K (no cvt chains)
//  - rank-by-broadcast selection (no iterative extraction)
//  - bank-conflict-free S: row stride 2068 u16; reads as b32 at 4*lane stride
// ---------------------------------------------------------------------------
__global__ __launch_bounds__(512, 4) void attn_topk(
    const u16* __restrict__ Qb, const u16* __restrict__ Kb,
    const u16* __restrict__ Ql, const u16* __restrict__ Kl,
    const double* __restrict__ Qd, const double* __restrict__ Kd,
    const u16* __restrict__ Vb, u16* __restrict__ Ab)
{
  __shared__ alignas(16) u16 S[16][2068];   // 66.2 KB, padded stride
  __shared__ u16 selS[16][64];
  __shared__ u16 bndS[16][64];
  __shared__ int cnts[16][2];

  const int lid = blockIdx.y * 128 + blockIdx.x;
  const int bh  = (lid & 7) * 4 + (lid >> 10);
  const int qb  = (lid >> 3) & 127;
  const size_t base = (size_t)(bh >> 4) * 2097152 + (size_t)(bh & 15) * 131072;
  const int q0 = qb * 16;
  const int tid = threadIdx.x, w = tid >> 6, lane = tid & 63;
  const int l15 = lane & 15, lg = lane >> 4;

  // Phase 1: 3-pass approx scores; wave w covers kk in [w*256, w*256+256)
  v8s a0  = *(const v8s*)(Qb + base + (q0 + l15)*64 + lg*8);
  v8s a1  = *(const v8s*)(Qb + base + (q0 + l15)*64 + lg*8 + 32);
  v8s a0l = *(const v8s*)(Ql + base + (q0 + l15)*64 + lg*8);
  v8s a1l = *(const v8s*)(Ql + base + (q0 + l15)*64 + lg*8 + 32);
  for (int kt = 0; kt < 16; ++kt){
    int kk0 = w*256 + kt*16;
    v8s b0  = *(const v8s*)(Kb + base + (kk0 + l15)*64 + lg*8);
    v8s b1  = *(const v8s*)(Kb + base + (kk0 + l15)*64 + lg*8 + 32);
    v8s b0l = *(const v8s*)(Kl + base + (kk0 + l15)*64 + lg*8);
    v8s b1l = *(const v8s*)(Kl + base + (kk0 + l15)*64 + lg*8 + 32);
    v4f acc = {0.f,0.f,0.f,0.f};
    acc = __builtin_amdgcn_mfma_f32_16x16x32_bf16(a0l, b0,  acc, 0, 0, 0);
    acc = __builtin_amdgcn_mfma_f32_16x16x32_bf16(a0,  b0l, acc, 0, 0, 0);
    acc = __builtin_amdgcn_mfma_f32_16x16x32_bf16(a0,  b0,  acc, 0, 0, 0);
    acc = __builtin_amdgcn_mfma_f32_16x16x32_bf16(a1l, b1,  acc, 0, 0, 0);
    acc = __builtin_amdgcn_mfma_f32_16x16x32_bf16(a1,  b1l, acc, 0, 0, 0);
    acc = __builtin_amdgcn_mfma_f32_16x16x32_bf16(a1,  b1,  acc, 0, 0, 0);
#pragma unroll
    for (int e = 0; e < 4; ++e) S[lg*4 + e][kk0 + l15] = f2bf(acc[e] * 0.125f);
  }
  if (tid < 32) cnts[tid >> 1][tid & 1] = 0;
  __syncthreads();   // the ONLY block-wide barrier

  for (int rr = 0; rr < 2; ++rr){
    const int r = w*2 + rr;     // wave w owns rows 2w, 2w+1 exclusively
    selS[r][lane] = 0;          // safety fill

    // Phase 2a: unpack 32 vals/lane, conflict-free b32 reads
    float vals[32];
    const char* rowp = (const char*)&S[r][0];
#pragma unroll
    for (int mm = 0; mm < 16; ++mm){
      u32 wd = *(const u32*)(rowp + 4*lane + 256*mm);
      vals[2*mm]   = bf2f((u16)(wd & 0xFFFFu));
      vals[2*mm+1] = bf2f((u16)(wd >> 16));
    }

    // Phase 2b: ballot histogram, 16 thresholds 1.5 + 0.0625*j
    int cc[16];
#pragma unroll
    for (int j = 0; j < 16; ++j){
      float T = 1.5f + 0.0625f*(float)j;
      int c = 0;
#pragma unroll
      for (int m = 0; m < 32; ++m) c += (int)__popcll(__ballot(vals[m] >= T));
      cc[j] = c;
    }
    int jstar = 16;
#pragma unroll
    for (int j = 15; j >= 0; --j) if (cc[j] < 64) jstar = j;

    float Tb, Ub;
    if (jstar > 0 && jstar < 16){
      Tb = 1.5f + 0.0625f*(float)(jstar-1);
      Ub = Tb + 0.0625f;
    } else {
      // Fallback (astronomically rare): exact bf16 64th via ballot binsearch
      u32 t64v = 0;
      for (int bit = 15; bit >= 0; --bit){
        u32 tt = t64v | (1u << bit);
        int c = 0;
#pragma unroll
        for (int m = 0; m < 32; ++m){
          u16 sb = f2bf(vals[m]);
          u32 key = (sb & 0x8000u) ? (u32)((~sb) & 0xFFFFu) : (u32)(sb | 0x8000u);
          c += (int)__popcll(__ballot(key >= tt));
        }
        if (c >= 64) t64v = tt;
      }
      u16 s64b = (t64v & 0x8000u) ? (u16)(t64v ^ 0x8000u) : (u16)((~t64v) & 0xFFFFu);
      float s64f = bf2f(s64b);
      Tb = s64f; Ub = s64f;
    }
    const float A   = Ub + 0.012f;   // 2*delta, delta = 0.006
    const float Blo = Tb - 0.012f;

    // Phase 3: classify auto (> A) / band ([Blo, A])
#pragma unroll
    for (int m = 0; m < 32; ++m){
      float vv = vals[m];
      int col = 128*(m >> 1) + 2*lane + (m & 1);
      if (vv > A){
        int p = atomicAdd(&cnts[r][0], 1);
        if (p < 64) selS[r][p] = (u16)col;
      } else if (vv >= Blo){
        int p = atomicAdd(&cnts[r][1], 1);
        if (p < 64) bndS[r][p] = (u16)col;
      }
    }
    asm volatile("s_waitcnt lgkmcnt(0)" ::: "memory");
    __builtin_amdgcn_sched_barrier(0);
    int na = cnts[r][0]; na = na > 64 ? 64 : na;
    int nb = cnts[r][1]; nb = nb > 64 ? 64 : nb;

    // Phase 4: fp64 rescore, candidate-per-lane, direct double loads
    int ki = (lane < nb) ? (int)bndS[r][lane] : 0;
    const double* Krow = Kd + base + (size_t)ki*64;
    const double* Qrow = Qd + base + (size_t)(q0 + r)*64;   // uniform addr -> broadcast
    double ex = 0.0;
#pragma unroll 16
    for (int d = 0; d < 64; ++d) ex += Qrow[d] * Krow[d];
    double myv = (lane < nb) ? ex : -1.0e300;
    int    myi = (lane < nb) ? ki : 0x7FFFFFFF;

    // Phase 5: rank-by-broadcast; fill selS[na + rank] for rank < need
    int need = 64 - na; if (need > nb) need = nb;
    int rank = 0;
    for (int j = 0; j < nb; ++j){
      double ov = __shfl(myv, j); int oi = __shfl(myi, j);
      rank += (ov > myv || (ov == myv && oi < myi)) ? 1 : 0;
    }
    if (lane < nb && rank < need) selS[r][na + rank] = (u16)myi;
    asm volatile("s_waitcnt lgkmcnt(0)" ::: "memory");
    __builtin_amdgcn_sched_barrier(0);

    // Phase 6: softmax over the 64 selected (approx scores)
    int selidx = (int)selS[r][lane];
    float sc = bf2f(S[r][selidx]);
    float mx = sc;
#pragma unroll
    for (int off = 32; off; off >>= 1) mx = fmaxf(mx, __shfl_xor(mx, off));
    float p = expf(sc - mx);
    float Z = p;
#pragma unroll
    for (int off = 32; off; off >>= 1) Z += __shfl_xor(Z, off);
    float pp = p / Z;

    // Phase 7: PV (lane = d), bf16 V, probs/idx via shfl broadcast
    const u16* Vh = Vb + base;
    float o0 = 0.f, o1 = 0.f;
#pragma unroll 8
    for (int i = 0; i < 64; i += 2){
      int i0x = __shfl(selidx, i);     float p0x = __shfl(pp, i);
      int i1x = __shfl(selidx, i + 1); float p1x = __shfl(pp, i + 1);
      o0 += p0x * bf2f(Vh[(size_t)i0x*64 + lane]);
      o1 += p1x * bf2f(Vh[(size_t)i1x*64 + lane]);
    }
    Ab[base + (size_t)(q0 + r)*64 + lane] = f2bf(o0 + o1);
  }
}

// ---------------------------------------------------------------------------
extern "C" void kernel_launch(void* const* d_in, const int* in_sizes, int n_in,
                              void* d_out, int out_size, void* d_ws, size_t ws_size,
                              hipStream_t stream)
{
  (void)in_sizes; (void)n_in; (void)out_size; (void)ws_size;
  const float* q  = (const float*)d_in[0];
  const float* k  = (const float*)d_in[1];
  const float* v  = (const float*)d_in[2];
  const float* Wq = (const float*)d_in[3];
  const float* bq = (const float*)d_in[4];
  const float* Wk = (const float*)d_in[5];
  const float* bk = (const float*)d_in[6];
  const float* Wv = (const float*)d_in[7];
  const float* bv = (const float*)d_in[8];
  const float* Wo = (const float*)d_in[9];
  const float* bo = (const float*)d_in[10];

  char* ws = (char*)d_ws;
  const size_t MB = 1048576;
  double* Qd  = (double*)(ws);             // 32 MB
  double* Kd  = (double*)(ws + 32*MB);     // 32 MB
  u16*    Qb  = (u16*)  (ws + 64*MB);      // 8 MB  (hi)
  u16*    Kb  = (u16*)  (ws + 72*MB);      // 8 MB  (hi)
  u16*    Ql  = (u16*)  (ws + 80*MB);      // 8 MB  (lo)
  u16*    Kl  = (u16*)  (ws + 88*MB);      // 8 MB  (lo)
  u16*    Abf = (u16*)  (ws + 96*MB);      // 8 MB
  s8*     dact= (s8*)   (ws + 104*MB);     // 16 MB (4 planes; dead after K-proj)
  u16*    Vbf = (u16*)  (ws + 104*MB);     // 8 MB  (aliases dact, written after)
  s8*     dw  = (s8*)   (ws + 120*MB);     // 4 MB  -> total 124 MB

  quant_digits<<<2048, 256, 0, stream>>>(q,  dact, 4194304, 134217728.0f, 7.75f);    // 2^27
  quant_digits<<<512,  256, 0, stream>>>(Wq, dw,   1048576, 4294967296.0f, 0.2495f); // 2^32
  gemm_i8<<<dim3(128, 32), 256, 0, stream>>>(dact, dw, bq, Qd, Qb, Ql);
  quant_digits<<<2048, 256, 0, stream>>>(k,  dact, 4194304, 134217728.0f, 7.75f);
  quant_digits<<<512,  256, 0, stream>>>(Wk, dw,   1048576, 4294967296.0f, 0.2495f);
  gemm_i8<<<dim3(128, 32), 256, 0, stream>>>(dact, dw, bk, Kd, Kb, Kl);
  gemm_bf16k<0,1><<<dim3(128, 32), 256, 0, stream>>>(v, Wv, bv, Vbf);
  attn_topk<<<dim3(128, 32), 512, 0, stream>>>(Qb, Kb, Ql, Kl, Qd, Kd, Vbf, Abf);
  gemm_bf16k<1,0><<<dim3(128, 32), 256, 0, stream>>>(Abf, Wo, bo, d_out);
}

// Round 4
// 703.741 us; speedup vs baseline: 2.1635x; 1.1487x over previous
//
#include <hip/hip_runtime.h>
#include <stdint.h>

using u8  = unsigned char;
using s8  = signed char;
using u16 = unsigned short;
using u32 = unsigned int;
using u64 = unsigned long long;

typedef int   v4i __attribute__((ext_vector_type(4)));
typedef float v4f __attribute__((ext_vector_type(4)));
typedef short v8s __attribute__((ext_vector_type(8)));

__device__ __forceinline__ u16 f2bf(float f){
  u32 u = __builtin_bit_cast(u32, f);
  u32 r = (u + 0x7FFFu + ((u >> 16) & 1u)) >> 16;
  return (u16)r;
}
__device__ __forceinline__ float bf2f(u16 b){
  u32 u = ((u32)b) << 16;
  return __builtin_bit_cast(float, u);
}

// ---------------------------------------------------------------------------
// Quantize fp32 -> 4 signed-i8 digit planes of X = rint(x*scale). Exact.
// ---------------------------------------------------------------------------
__global__ __launch_bounds__(256) void quant_digits(
    const float* __restrict__ in, s8* __restrict__ dig, int n, float scale, float clampv)
{
  int t = blockIdx.x * 256 + threadIdx.x;
  int n8 = n >> 3;
  if (t >= n8) return;
  const float4* inv = (const float4*)in;
  float4 a = inv[2*t], b = inv[2*t+1];
  float xs[8] = {a.x,a.y,a.z,a.w,b.x,b.y,b.z,b.w};
  u64 p0=0,p1=0,p2=0,p3=0;
#pragma unroll
  for (int j=0;j<8;j++){
    float xv = fminf(fmaxf(xs[j], -clampv), clampv);
    int X = (int)rintf(xv * scale);
    int d0 = (int)(s8)(X & 255); X = (X - d0) >> 8;
    int d1 = (int)(s8)(X & 255); X = (X - d1) >> 8;
    int d2 = (int)(s8)(X & 255); X = (X - d2) >> 8;
    int d3 = X;
    p0 |= ((u64)(u8)(s8)d0) << (8*j);
    p1 |= ((u64)(u8)(s8)d1) << (8*j);
    p2 |= ((u64)(u8)(s8)d2) << (8*j);
    p3 |= ((u64)(u8)(s8)d3) << (8*j);
  }
  u64* o = (u64*)dig;
  size_t np8 = (size_t)n8;
  o[t] = p0; o[np8 + t] = p1; o[2*np8 + t] = p2; o[3*np8 + t] = p3;
}

// ---------------------------------------------------------------------------
// Precise GEMM via exact fixed-point i8 MFMA. Epilogue writes:
//   Cd: exact double, Cb: bf16 hi, Cl: bf16 lo residual.
// ---------------------------------------------------------------------------
#define MFMA_I8(c, a, b) asm volatile("v_mfma_i32_16x16x64_i8 %0, %1, %2, %0" : "+v"(c) : "v"(a), "v"(b))

__global__ __launch_bounds__(256) void gemm_i8(
    const s8* __restrict__ Ad, const s8* __restrict__ Wd, const float* __restrict__ bias,
    double* __restrict__ Cd, u16* __restrict__ Cb, u16* __restrict__ Cl)
{
  __shared__ alignas(16) s8 As[4][32][80];
  __shared__ alignas(16) s8 Bs[4][32][80];
  const int i0 = blockIdx.x * 32, o0 = blockIdx.y * 32;
  const int t = threadIdx.x, w = t >> 6, lane = t & 63;
  const int wr = w >> 1, wc = w & 1, l15 = lane & 15, lg = lane >> 4;
  const size_t APL = 4194304, WPL = 1048576;

  v4i c0={0,0,0,0}, c1={0,0,0,0}, c2={0,0,0,0}, c3={0,0,0,0}, c4={0,0,0,0};

  for (int kt = 0; kt < 16; ++kt){
#pragma unroll
    for (int j = 0; j < 2; ++j){
      int cid = t*2 + j;
      int p = cid >> 7, rem = cid & 127;
      int row = rem >> 2, c16 = (rem & 3) << 4;
      int4 av = *(const int4*)(Ad + (size_t)p*APL + (size_t)(i0+row)*1024 + kt*64 + c16);
      *(int4*)&As[p][row][c16] = av;
      int4 bv = *(const int4*)(Wd + (size_t)p*WPL + (size_t)(o0+row)*1024 + kt*64 + c16);
      *(int4*)&Bs[p][row][c16] = bv;
    }
    __syncthreads();
    v4i a0 = *(const v4i*)&As[0][wr*16+l15][lg*16];
    v4i a1 = *(const v4i*)&As[1][wr*16+l15][lg*16];
    v4i a2 = *(const v4i*)&As[2][wr*16+l15][lg*16];
    v4i a3 = *(const v4i*)&As[3][wr*16+l15][lg*16];
    v4i b0 = *(const v4i*)&Bs[0][wc*16+l15][lg*16];
    v4i b1 = *(const v4i*)&Bs[1][wc*16+l15][lg*16];
    v4i b2 = *(const v4i*)&Bs[2][wc*16+l15][lg*16];
    v4i b3 = *(const v4i*)&Bs[3][wc*16+l15][lg*16];
    MFMA_I8(c0, a0, b2); MFMA_I8(c0, a1, b1); MFMA_I8(c0, a2, b0);
    MFMA_I8(c1, a0, b3); MFMA_I8(c1, a1, b2); MFMA_I8(c1, a2, b1); MFMA_I8(c1, a3, b0);
    MFMA_I8(c2, a1, b3); MFMA_I8(c2, a2, b2); MFMA_I8(c2, a3, b1);
    MFMA_I8(c3, a2, b3); MFMA_I8(c3, a3, b2);
    MFMA_I8(c4, a3, b3);
    __syncthreads();
  }
  const int oc = o0 + wc*16 + l15;
  const double bv = (double)bias[oc];
#pragma unroll
  for (int e = 0; e < 4; ++e){
    double val = (double)c0[e]*0x1p-43 + (double)c1[e]*0x1p-35 + (double)c2[e]*0x1p-27
               + (double)c3[e]*0x1p-19 + (double)c4[e]*0x1p-11 + bv;
    int orow = i0 + wr*16 + lg*4 + e;
    size_t idx = (size_t)orow*1024 + oc;
    Cd[idx] = val;
    float hi = (float)val;
    u16 hb = f2bf(hi);
    float lof = (float)(val - (double)bf2f(hb));
    Cb[idx] = hb;
    Cl[idx] = f2bf(lof);
  }
}

// ---------------------------------------------------------------------------
// bf16 GEMM (A fp32->bf16 or A bf16), out fp32 or bf16.
// ---------------------------------------------------------------------------
template<int ABF16, int OUTBF>
__global__ __launch_bounds__(256) void gemm_bf16k(
    const void* __restrict__ Ap, const float* __restrict__ W, const float* __restrict__ bias,
    void* __restrict__ C)
{
  __shared__ alignas(16) u16 As[32][72];
  __shared__ alignas(16) u16 Bs[32][72];
  const int i0 = blockIdx.x * 32, o0 = blockIdx.y * 32;
  const int t = threadIdx.x, w = t >> 6, lane = t & 63;
  const int wr = w >> 1, wc = w & 1, l15 = lane & 15, lg = lane >> 4;
  const int row = t >> 3, c8 = (t & 7) * 8;
  v4f acc = {0.f,0.f,0.f,0.f};
  for (int kt = 0; kt < 16; ++kt){
    if (ABF16){
      v8s x = *(const v8s*)((const u16*)Ap + (size_t)(i0+row)*1024 + kt*64 + c8);
      *(v8s*)&As[row][c8] = x;
    } else {
      const float* A = (const float*)Ap;
      const float4 x0 = *(const float4*)(A + (size_t)(i0+row)*1024 + kt*64 + c8);
      const float4 x1 = *(const float4*)(A + (size_t)(i0+row)*1024 + kt*64 + c8 + 4);
      v8s pk;
      pk[0]=(short)f2bf(x0.x); pk[1]=(short)f2bf(x0.y); pk[2]=(short)f2bf(x0.z); pk[3]=(short)f2bf(x0.w);
      pk[4]=(short)f2bf(x1.x); pk[5]=(short)f2bf(x1.y); pk[6]=(short)f2bf(x1.z); pk[7]=(short)f2bf(x1.w);
      *(v8s*)&As[row][c8] = pk;
    }
    {
      const float4 y0 = *(const float4*)(W + (size_t)(o0+row)*1024 + kt*64 + c8);
      const float4 y1 = *(const float4*)(W + (size_t)(o0+row)*1024 + kt*64 + c8 + 4);
      v8s pk;
      pk[0]=(short)f2bf(y0.x); pk[1]=(short)f2bf(y0.y); pk[2]=(short)f2bf(y0.z); pk[3]=(short)f2bf(y0.w);
      pk[4]=(short)f2bf(y1.x); pk[5]=(short)f2bf(y1.y); pk[6]=(short)f2bf(y1.z); pk[7]=(short)f2bf(y1.w);
      *(v8s*)&Bs[row][c8] = pk;
    }
    __syncthreads();
    v8s a0 = *(const v8s*)&As[wr*16+l15][lg*8];
    v8s a1 = *(const v8s*)&As[wr*16+l15][lg*8+32];
    v8s b0 = *(const v8s*)&Bs[wc*16+l15][lg*8];
    v8s b1 = *(const v8s*)&Bs[wc*16+l15][lg*8+32];
    acc = __builtin_amdgcn_mfma_f32_16x16x32_bf16(a0, b0, acc, 0, 0, 0);
    acc = __builtin_amdgcn_mfma_f32_16x16x32_bf16(a1, b1, acc, 0, 0, 0);
    __syncthreads();
  }
  const int oc = o0 + wc*16 + l15;
  const float bvv = bias[oc];
#pragma unroll
  for (int e=0;e<4;e++){
    int orow = i0 + wr*16 + lg*4 + e;
    size_t idx = (size_t)orow*1024 + oc;
    if (OUTBF) ((u16*)C)[idx] = f2bf(acc[e] + bvv);
    else       ((float*)C)[idx] = acc[e] + bvv;
  }
}

// ---------------------------------------------------------------------------
// Fused top-k attention, round 4:
//  - fixed prefilter T0=1.5 (one cmp/value) -> ~137 candidates of 2048;
//    runtime guarantee check (t64 >= T0+0.0125) + uniform fallback rescan
//  - all compaction via ballot-prefix (ZERO LDS atomics)
//  - candidate/sel/band lists live in the dead S row (no extra LDS)
//  - scores ride packed (bf16<<16|idx): no scattered S gathers
//  - 3 independent MFMA chains (depth 2) in phase 1
//  - 4-way split fp64 accumulators in rescore
// ---------------------------------------------------------------------------
__global__ __launch_bounds__(512, 4) void attn_topk(
    const u16* __restrict__ Qb, const u16* __restrict__ Kb,
    const u16* __restrict__ Ql, const u16* __restrict__ Kl,
    const double* __restrict__ Qd, const double* __restrict__ Kd,
    const u16* __restrict__ Vb, u16* __restrict__ Ab)
{
  __shared__ alignas(16) u16 S[16][2068];   // 66.2 KB, padded stride

  const int lid = blockIdx.y * 128 + blockIdx.x;
  const int bh  = (lid & 7) * 4 + (lid >> 10);
  const int qb  = (lid >> 3) & 127;
  const size_t base = (size_t)(bh >> 4) * 2097152 + (size_t)(bh & 15) * 131072;
  const int q0 = qb * 16;
  const int tid = threadIdx.x, w = tid >> 6, lane = tid & 63;
  const int l15 = lane & 15, lg = lane >> 4;
  const u64 ltmask = (1ull << lane) - 1ull;

  // Phase 1: 3-pass approx scores, 3 independent MFMA chains
  v8s a0  = *(const v8s*)(Qb + base + (q0 + l15)*64 + lg*8);
  v8s a1  = *(const v8s*)(Qb + base + (q0 + l15)*64 + lg*8 + 32);
  v8s a0l = *(const v8s*)(Ql + base + (q0 + l15)*64 + lg*8);
  v8s a1l = *(const v8s*)(Ql + base + (q0 + l15)*64 + lg*8 + 32);
  const v4f vzero = {0.f,0.f,0.f,0.f};
#pragma unroll 2
  for (int kt = 0; kt < 16; ++kt){
    int kk0 = w*256 + kt*16;
    v8s b0  = *(const v8s*)(Kb + base + (kk0 + l15)*64 + lg*8);
    v8s b1  = *(const v8s*)(Kb + base + (kk0 + l15)*64 + lg*8 + 32);
    v8s b0l = *(const v8s*)(Kl + base + (kk0 + l15)*64 + lg*8);
    v8s b1l = *(const v8s*)(Kl + base + (kk0 + l15)*64 + lg*8 + 32);
    v4f hh = __builtin_amdgcn_mfma_f32_16x16x32_bf16(a0,  b0,  vzero, 0, 0, 0);
    v4f hl = __builtin_amdgcn_mfma_f32_16x16x32_bf16(a0,  b0l, vzero, 0, 0, 0);
    v4f lh = __builtin_amdgcn_mfma_f32_16x16x32_bf16(a0l, b0,  vzero, 0, 0, 0);
    hh = __builtin_amdgcn_mfma_f32_16x16x32_bf16(a1,  b1,  hh, 0, 0, 0);
    hl = __builtin_amdgcn_mfma_f32_16x16x32_bf16(a1,  b1l, hl, 0, 0, 0);
    lh = __builtin_amdgcn_mfma_f32_16x16x32_bf16(a1l, b1,  lh, 0, 0, 0);
#pragma unroll
    for (int e = 0; e < 4; ++e)
      S[lg*4 + e][kk0 + l15] = f2bf(((hh[e] + hl[e]) + lh[e]) * 0.125f);
  }
  __syncthreads();   // the ONLY block-wide barrier

  for (int rr = 0; rr < 2; ++rr){
    const int r = w*2 + rr;     // wave w owns rows 2w, 2w+1 exclusively
    u32* rowu = (u32*)&S[r][0];

    // Phase 2a: unpack 32 vals/lane (conflict-free b32 reads); keep words
    float vals[32]; u32 wds[16];
    const char* rowp = (const char*)&S[r][0];
#pragma unroll
    for (int mm = 0; mm < 16; ++mm){
      u32 wd = *(const u32*)(rowp + 4*lane + 256*mm);
      wds[mm] = wd;
      vals[2*mm]   = bf2f((u16)(wd & 0xFFFFu));
      vals[2*mm+1] = bf2f((u16)(wd >> 16));
    }

    // Phase 2b: prefilter scan + compaction + binsearch, with fallback
    float T0 = 1.5f;
    u32 t64k = 0x3FEEu;          // ~1.86, only used on forced exit (never)
    int cstore = 0;
    u32 pk0 = 0, pk1 = 0, pk2 = 0;
    for (int attempt = 0; attempt < 6; ++attempt){
      int cnt = 0;
#pragma unroll
      for (int mm = 0; mm < 16; ++mm){
#pragma unroll
        for (int h = 0; h < 2; ++h){
          bool hit = vals[2*mm + h] >= T0;
          u64 mk = __ballot(hit);
          if (hit){
            int pos = cnt + (int)__popcll(mk & ltmask);
            if (pos < 192){
              u32 col = (u32)(128*mm + 2*lane + h);
              u32 pk = h ? ((wds[mm] & 0xFFFF0000u) | col) : ((wds[mm] << 16) | col);
              rowu[pos] = pk;
            }
          }
          cnt += (int)__popcll(mk);
        }
      }
      if (cnt > 192){ T0 += 0.25f; continue; }
      if (cnt < 64) { T0 -= 0.50f; continue; }
      cstore = cnt;
      asm volatile("s_waitcnt lgkmcnt(0)" ::: "memory");
      __builtin_amdgcn_sched_barrier(0);
      pk0 = (lane < cstore)       ? rowu[lane]       : 0u;
      pk1 = (64 + lane < cstore)  ? rowu[64 + lane]  : 0u;
      pk2 = (128 + lane < cstore) ? rowu[128 + lane] : 0u;
      u32 k0 = pk0 >> 16, k1 = pk1 >> 16, k2 = pk2 >> 16;
      u32 tv = 0;
      for (int bit = 14; bit >= 0; --bit){
        u32 tt = tv | (1u << bit);
        int c = (int)__popcll(__ballot(k0 >= tt))
              + (int)__popcll(__ballot(k1 >= tt))
              + (int)__popcll(__ballot(k2 >= tt));
        if (c >= 64) tv = tt;
      }
      t64k = tv;
      if (bf2f((u16)t64k) < T0 + 0.0125f){ T0 -= 0.50f; continue; }
      break;
    }

    // Phase 3: classify candidates (<=3/lane) into auto/band, ballot-prefix
    const float t64f = bf2f((u16)t64k);
    const float thi = t64f + 0.012f, tlo = t64f - 0.012f;
    int na = 0, nb = 0;
#pragma unroll
    for (int s = 0; s < 3; ++s){
      u32 pk = (s == 0) ? pk0 : ((s == 1) ? pk1 : pk2);
      bool act = (64*s + lane) < cstore;
      float v = bf2f((u16)(pk >> 16));
      bool aut = act && (v > thi);
      bool ban = act && !aut && (v >= tlo);
      u64 ma = __ballot(aut);
      if (aut){
        int pos = na + (int)__popcll(ma & ltmask);
        if (pos < 64) rowu[192 + pos] = pk;
      }
      na += (int)__popcll(ma);
      u64 mb = __ballot(ban);
      if (ban){
        int pos = nb + (int)__popcll(mb & ltmask);
        if (pos < 64) rowu[256 + pos] = pk;
      }
      nb += (int)__popcll(mb);
    }
    if (na > 64) na = 64;
    if (nb > 64) nb = 64;
    asm volatile("s_waitcnt lgkmcnt(0)" ::: "memory");
    __builtin_amdgcn_sched_barrier(0);

    // Phase 4: fp64 rescore of band (candidate-per-lane, 4 split accums)
    u32 bpk = (lane < nb) ? rowu[256 + lane] : 0u;
    int ki = (int)(bpk & 0x7FFu);
    const double* Krow = Kd + base + (size_t)ki*64;
    const double* Qrow = Qd + base + (size_t)(q0 + r)*64;
    double x0 = 0.0, x1 = 0.0, x2 = 0.0, x3 = 0.0;
#pragma unroll 8
    for (int d = 0; d < 64; d += 4){
      x0 = fma(Qrow[d],   Krow[d],   x0);
      x1 = fma(Qrow[d+1], Krow[d+1], x1);
      x2 = fma(Qrow[d+2], Krow[d+2], x2);
      x3 = fma(Qrow[d+3], Krow[d+3], x3);
    }
    double myv = (lane < nb) ? ((x0 + x1) + (x2 + x3)) : -1.0e300;
    int    myi = (lane < nb) ? ki : 0x7FFFFFFF;

    // Phase 5: rank-by-broadcast; write sel[na + rank] for rank < need
    int need = 64 - na; if (need > nb) need = nb;
    int rank = 0;
    for (int j = 0; j < nb; ++j){
      double ov = __shfl(myv, j); int oi = __shfl(myi, j);
      rank += (ov > myv || (ov == myv && oi < myi)) ? 1 : 0;
    }
    if (lane < nb && rank < need) rowu[192 + na + rank] = bpk;
    asm volatile("s_waitcnt lgkmcnt(0)" ::: "memory");
    __builtin_amdgcn_sched_barrier(0);

    // Phase 6: softmax over the 64 selected (packed approx scores)
    u32 spk = rowu[192 + lane];
    int selidx = (int)(spk & 0x7FFu);
    float sc = bf2f((u16)(spk >> 16));
    float mx = sc;
#pragma unroll
    for (int off = 32; off; off >>= 1) mx = fmaxf(mx, __shfl_xor(mx, off));
    float p = expf(sc - mx);
    float Z = p;
#pragma unroll
    for (int off = 32; off; off >>= 1) Z += __shfl_xor(Z, off);
    float pp = p / Z;

    // Phase 7: PV (lane = d), bf16 V, probs/idx via readlane broadcast
    const u16* Vh = Vb + base;
    float o0 = 0.f, o1 = 0.f;
#pragma unroll 8
    for (int i = 0; i < 64; i += 2){
      int i0x = __shfl(selidx, i);     float p0x = __shfl(pp, i);
      int i1x = __shfl(selidx, i + 1); float p1x = __shfl(pp, i + 1);
      o0 += p0x * bf2f(Vh[(size_t)i0x*64 + lane]);
      o1 += p1x * bf2f(Vh[(size_t)i1x*64 + lane]);
    }
    Ab[base + (size_t)(q0 + r)*64 + lane] = f2bf(o0 + o1);
  }
}

// ---------------------------------------------------------------------------
extern "C" void kernel_launch(void* const* d_in, const int* in_sizes, int n_in,
                              void* d_out, int out_size, void* d_ws, size_t ws_size,
                              hipStream_t stream)
{
  (void)in_sizes; (void)n_in; (void)out_size; (void)ws_size;
  const float* q  = (const float*)d_in[0];
  const float* k  = (const float*)d_in[1];
  const float* v  = (const float*)d_in[2];
  const float* Wq = (const float*)d_in[3];
  const float* bq = (const float*)d_in[4];
  const float* Wk = (const float*)d_in[5];
  const float* bk = (const float*)d_in[6];
  const float* Wv = (const float*)d_in[7];
  const float* bv = (const float*)d_in[8];
  const float* Wo = (const float*)d_in[9];
  const float* bo = (const float*)d_in[10];

  char* ws = (char*)d_ws;
  const size_t MB = 1048576;
  double* Qd  = (double*)(ws);             // 32 MB
  double* Kd  = (double*)(ws + 32*MB);     // 32 MB
  u16*    Qb  = (u16*)  (ws + 64*MB);      // 8 MB  (hi)
  u16*    Kb  = (u16*)  (ws + 72*MB);      // 8 MB  (hi)
  u16*    Ql  = (u16*)  (ws + 80*MB);      // 8 MB  (lo)
  u16*    Kl  = (u16*)  (ws + 88*MB);      // 8 MB  (lo)
  u16*    Abf = (u16*)  (ws + 96*MB);      // 8 MB
  s8*     dact= (s8*)   (ws + 104*MB);     // 16 MB (dead after K-proj)
  u16*    Vbf = (u16*)  (ws + 104*MB);     // 8 MB  (aliases dact, written after)
  s8*     dw  = (s8*)   (ws + 120*MB);     // 4 MB  -> total 124 MB

  quant_digits<<<2048, 256, 0, stream>>>(q,  dact, 4194304, 134217728.0f, 7.75f);    // 2^27
  quant_digits<<<512,  256, 0, stream>>>(Wq, dw,   1048576, 4294967296.0f, 0.2495f); // 2^32
  gemm_i8<<<dim3(128, 32), 256, 0, stream>>>(dact, dw, bq, Qd, Qb, Ql);
  quant_digits<<<2048, 256, 0, stream>>>(k,  dact, 4194304, 134217728.0f, 7.75f);
  quant_digits<<<512,  256, 0, stream>>>(Wk, dw,   1048576, 4294967296.0f, 0.2495f);
  gemm_i8<<<dim3(128, 32), 256, 0, stream>>>(dact, dw, bk, Kd, Kb, Kl);
  gemm_bf16k<0,1><<<dim3(128, 32), 256, 0, stream>>>(v, Wv, bv, Vbf);
  attn_topk<<<dim3(128, 32), 512, 0, stream>>>(Qb, Kb, Ql, Kl, Qd, Kd, Vbf, Abf);
  gemm_bf16k<1,0><<<dim3(128, 32), 256, 0, stream>>>(Abf, Wo, bo, d_out);
}